// Round 1
// baseline (2845.502 us; speedup 1.0000x reference)
//
#include <hip/hip_runtime.h>

#define N_GRID 128
#define N_GRID3 (N_GRID * N_GRID * N_GRID)

constexpr int   N_PART   = 500000;
constexpr float DT       = 0.0002f;
constexpr float DX       = 1.0f / 128.0f;
constexpr float INV_DX   = 128.0f;
constexpr float P_MASS   = 5.9604644775390625e-05f;   // (DX*0.5)^3 * 1000
constexpr float AFF_COEF = -7.8125e-07f;              // -DT * P_VOL * 4 * INV_DX^2
constexpr float GRAVITY  = 9.8f;
constexpr int   BOUND    = 3;
constexpr float C_SCALE  = 65536.0f;                  // 4 * INV_DX^2

// ---------------- P2G: scatter particle momentum/mass to grid ----------------
__global__ __launch_bounds__(256) void mpm_p2g(
    const float* __restrict__ x, const float* __restrict__ v,
    const float* __restrict__ C, const float* __restrict__ stress,
    float* __restrict__ grid /* [N_GRID3][4] */) {
  int n = blockIdx.x * blockDim.x + threadIdx.x;
  if (n >= N_PART) return;

  float px = x[n * 3 + 0], py = x[n * 3 + 1], pz = x[n * 3 + 2];
  float gx = px * INV_DX, gy = py * INV_DX, gz = pz * INV_DX;
  int bx = (int)floorf(gx - 0.5f);
  int by = (int)floorf(gy - 0.5f);
  int bz = (int)floorf(gz - 0.5f);
  float fx = gx - (float)bx, fy = gy - (float)by, fz = gz - (float)bz;

  float wx[3], wy[3], wz[3];
  wx[0] = 0.5f * (1.5f - fx) * (1.5f - fx);
  wx[1] = 0.75f - (fx - 1.0f) * (fx - 1.0f);
  wx[2] = 0.5f * (fx - 0.5f) * (fx - 0.5f);
  wy[0] = 0.5f * (1.5f - fy) * (1.5f - fy);
  wy[1] = 0.75f - (fy - 1.0f) * (fy - 1.0f);
  wy[2] = 0.5f * (fy - 0.5f) * (fy - 0.5f);
  wz[0] = 0.5f * (1.5f - fz) * (1.5f - fz);
  wz[1] = 0.75f - (fz - 1.0f) * (fz - 1.0f);
  wz[2] = 0.5f * (fz - 0.5f) * (fz - 0.5f);

  // affine = AFF_COEF*stress + P_MASS*C  (row-major 3x3)
  float aff[9];
#pragma unroll
  for (int i = 0; i < 9; ++i)
    aff[i] = AFF_COEF * stress[n * 9 + i] + P_MASS * C[n * 9 + i];

  float mvx = P_MASS * v[n * 3 + 0];
  float mvy = P_MASS * v[n * 3 + 1];
  float mvz = P_MASS * v[n * 3 + 2];

#pragma unroll
  for (int a = 0; a < 3; ++a) {
#pragma unroll
    for (int b = 0; b < 3; ++b) {
#pragma unroll
      for (int c = 0; c < 3; ++c) {
        float weight = wx[a] * wy[b] * wz[c];
        float dpx = ((float)a - fx) * DX;
        float dpy = ((float)b - fy) * DX;
        float dpz = ((float)c - fz) * DX;
        float m0 = mvx + aff[0] * dpx + aff[1] * dpy + aff[2] * dpz;
        float m1 = mvy + aff[3] * dpx + aff[4] * dpy + aff[5] * dpz;
        float m2 = mvz + aff[6] * dpx + aff[7] * dpy + aff[8] * dpz;
        int nx = min(max(bx + a, 0), N_GRID - 1);
        int ny = min(max(by + b, 0), N_GRID - 1);
        int nz = min(max(bz + c, 0), N_GRID - 1);
        int flat = (nx * N_GRID + ny) * N_GRID + nz;
        atomicAdd(&grid[flat * 4 + 0], weight * m0);
        atomicAdd(&grid[flat * 4 + 1], weight * m1);
        atomicAdd(&grid[flat * 4 + 2], weight * m2);
        atomicAdd(&grid[flat * 4 + 3], weight * P_MASS);
      }
    }
  }
}

// ---------------- grid update: normalize, gravity, boundary ----------------
__global__ __launch_bounds__(256) void mpm_grid_op(float* __restrict__ grid) {
  int i = blockIdx.x * blockDim.x + threadIdx.x;
  if (i >= N_GRID3) return;
  float4* g4 = (float4*)grid;
  float4 g = g4[i];
  float m = g.w;
  float vx = 0.0f, vy = 0.0f, vz = 0.0f;
  if (m > 0.0f) {
    float inv = 1.0f / fmaxf(m, 1e-10f);
    vx = g.x * inv;
    vy = g.y * inv;
    vz = g.z * inv;
    vy -= DT * GRAVITY;
  }
  int iz = i & (N_GRID - 1);
  int iy = (i >> 7) & (N_GRID - 1);
  int ix = i >> 14;
  if (ix < BOUND && vx < 0.0f) vx = 0.0f;
  if (ix >= N_GRID - BOUND && vx > 0.0f) vx = 0.0f;
  if (iy < BOUND && vy < 0.0f) vy = 0.0f;
  if (iy >= N_GRID - BOUND && vy > 0.0f) vy = 0.0f;
  if (iz < BOUND && vz < 0.0f) vz = 0.0f;
  if (iz >= N_GRID - BOUND && vz > 0.0f) vz = 0.0f;
  g4[i] = make_float4(vx, vy, vz, m);
}

// ---------------- G2P: gather grid velocity back to particles ----------------
__global__ __launch_bounds__(256) void mpm_g2p(
    const float* __restrict__ x, const float* __restrict__ F,
    const float* __restrict__ grid,
    float* __restrict__ out_x, float* __restrict__ out_v,
    float* __restrict__ out_C, float* __restrict__ out_F) {
  int n = blockIdx.x * blockDim.x + threadIdx.x;
  if (n >= N_PART) return;

  float px = x[n * 3 + 0], py = x[n * 3 + 1], pz = x[n * 3 + 2];
  float gx = px * INV_DX, gy = py * INV_DX, gz = pz * INV_DX;
  int bx = (int)floorf(gx - 0.5f);
  int by = (int)floorf(gy - 0.5f);
  int bz = (int)floorf(gz - 0.5f);
  float fx = gx - (float)bx, fy = gy - (float)by, fz = gz - (float)bz;

  float wx[3], wy[3], wz[3];
  wx[0] = 0.5f * (1.5f - fx) * (1.5f - fx);
  wx[1] = 0.75f - (fx - 1.0f) * (fx - 1.0f);
  wx[2] = 0.5f * (fx - 0.5f) * (fx - 0.5f);
  wy[0] = 0.5f * (1.5f - fy) * (1.5f - fy);
  wy[1] = 0.75f - (fy - 1.0f) * (fy - 1.0f);
  wy[2] = 0.5f * (fy - 0.5f) * (fy - 0.5f);
  wz[0] = 0.5f * (1.5f - fz) * (1.5f - fz);
  wz[1] = 0.75f - (fz - 1.0f) * (fz - 1.0f);
  wz[2] = 0.5f * (fz - 0.5f) * (fz - 0.5f);

  float vnx = 0.0f, vny = 0.0f, vnz = 0.0f;
  float Cn[9];
#pragma unroll
  for (int i = 0; i < 9; ++i) Cn[i] = 0.0f;

  const float4* g4 = (const float4*)grid;
#pragma unroll
  for (int a = 0; a < 3; ++a) {
#pragma unroll
    for (int b = 0; b < 3; ++b) {
#pragma unroll
      for (int c = 0; c < 3; ++c) {
        float weight = wx[a] * wy[b] * wz[c];
        float dpx = ((float)a - fx) * DX;
        float dpy = ((float)b - fy) * DX;
        float dpz = ((float)c - fz) * DX;
        int nx = min(max(bx + a, 0), N_GRID - 1);
        int ny = min(max(by + b, 0), N_GRID - 1);
        int nz = min(max(bz + c, 0), N_GRID - 1);
        int flat = (nx * N_GRID + ny) * N_GRID + nz;
        float4 g = g4[flat];
        vnx += weight * g.x;
        vny += weight * g.y;
        vnz += weight * g.z;
        Cn[0] += weight * g.x * dpx;
        Cn[1] += weight * g.x * dpy;
        Cn[2] += weight * g.x * dpz;
        Cn[3] += weight * g.y * dpx;
        Cn[4] += weight * g.y * dpy;
        Cn[5] += weight * g.y * dpz;
        Cn[6] += weight * g.z * dpx;
        Cn[7] += weight * g.z * dpy;
        Cn[8] += weight * g.z * dpz;
      }
    }
  }

#pragma unroll
  for (int i = 0; i < 9; ++i) Cn[i] *= C_SCALE;

  out_x[n * 3 + 0] = px + DT * vnx;
  out_x[n * 3 + 1] = py + DT * vny;
  out_x[n * 3 + 2] = pz + DT * vnz;
  out_v[n * 3 + 0] = vnx;
  out_v[n * 3 + 1] = vny;
  out_v[n * 3 + 2] = vnz;

  // A = I + DT*Cn ; F_next = A @ F
  float A[9];
#pragma unroll
  for (int i = 0; i < 9; ++i) A[i] = DT * Cn[i];
  A[0] += 1.0f; A[4] += 1.0f; A[8] += 1.0f;

  float Fl[9];
#pragma unroll
  for (int i = 0; i < 9; ++i) Fl[i] = F[n * 9 + i];

#pragma unroll
  for (int i = 0; i < 3; ++i) {
#pragma unroll
    for (int k = 0; k < 3; ++k) {
      float s = A[i * 3 + 0] * Fl[0 * 3 + k] +
                A[i * 3 + 1] * Fl[1 * 3 + k] +
                A[i * 3 + 2] * Fl[2 * 3 + k];
      out_F[n * 9 + i * 3 + k] = s;
    }
  }

#pragma unroll
  for (int i = 0; i < 9; ++i) out_C[n * 9 + i] = Cn[i];
}

extern "C" void kernel_launch(void* const* d_in, const int* in_sizes, int n_in,
                              void* d_out, int out_size, void* d_ws, size_t ws_size,
                              hipStream_t stream) {
  const float* x      = (const float*)d_in[0];
  const float* v      = (const float*)d_in[1];
  const float* C      = (const float*)d_in[2];
  const float* F      = (const float*)d_in[3];
  const float* stress = (const float*)d_in[4];

  float* out   = (float*)d_out;
  float* grid  = (float*)d_ws;  // N_GRID3 * 4 floats = 33.5 MB

  hipMemsetAsync(grid, 0, (size_t)N_GRID3 * 4 * sizeof(float), stream);

  int pblocks = (N_PART + 255) / 256;
  mpm_p2g<<<pblocks, 256, 0, stream>>>(x, v, C, stress, grid);

  int gblocks = (N_GRID3 + 255) / 256;
  mpm_grid_op<<<gblocks, 256, 0, stream>>>(grid);

  float* out_x = out;
  float* out_v = out + (size_t)N_PART * 3;
  float* out_C = out + (size_t)N_PART * 6;
  float* out_F = out + (size_t)N_PART * 6 + (size_t)N_PART * 9;
  mpm_g2p<<<pblocks, 256, 0, stream>>>(x, F, grid, out_x, out_v, out_C, out_F);
}

// Round 2
// 790.816 us; speedup vs baseline: 3.5982x; 3.5982x over previous
//
#include <hip/hip_runtime.h>

#define N_GRID 128
#define N_GRID3 (N_GRID * N_GRID * N_GRID)

constexpr int   N_PART   = 500000;
constexpr float DT       = 0.0002f;
constexpr float DX       = 1.0f / 128.0f;
constexpr float INV_DX   = 128.0f;
constexpr float P_MASS   = 5.9604644775390625e-05f;   // (DX*0.5)^3 * 1000
constexpr float AFF_COEF = -7.8125e-07f;              // -DT * P_VOL * 4 * INV_DX^2
constexpr float GRAVITY  = 9.8f;
constexpr int   BOUND    = 3;
constexpr float C_SCALE  = 65536.0f;                  // 4 * INV_DX^2

constexpr int NBLK  = 16;                 // blocks per axis (8 cells each)
constexpr int NBLK3 = NBLK * NBLK * NBLK; // 4096
constexpr int TILE  = 10;                 // nodes per axis in a block tile (8 + 2 halo)
constexpr int TILE3 = TILE * TILE * TILE; // 1000

// ---------------- pass 1: per-particle block id + histogram ----------------
__global__ __launch_bounds__(256) void k_count(const float* __restrict__ x,
                                               int* __restrict__ bid,
                                               int* __restrict__ cnt) {
  int n = blockIdx.x * 256 + threadIdx.x;
  if (n >= N_PART) return;
  int bx = (int)floorf(x[n * 3 + 0] * INV_DX - 0.5f) >> 3;
  int by = (int)floorf(x[n * 3 + 1] * INV_DX - 0.5f) >> 3;
  int bz = (int)floorf(x[n * 3 + 2] * INV_DX - 0.5f) >> 3;
  int b = (bx * NBLK + by) * NBLK + bz;
  bid[n] = b;
  atomicAdd(&cnt[b], 1);
}

// ---------------- pass 2: exclusive scan of 4096 bins (1 wave) ----------------
__global__ __launch_bounds__(64) void k_scan(const int* __restrict__ cnt,
                                             int* __restrict__ start,
                                             int* __restrict__ cursor) {
  int lane = threadIdx.x;  // 0..63, each lane owns 64 consecutive bins
  int base = lane * 64;
  int tot = 0;
  for (int i = 0; i < 64; ++i) tot += cnt[base + i];
  // inclusive wave scan -> exclusive
  int incl = tot;
  for (int d = 1; d < 64; d <<= 1) {
    int t = __shfl_up(incl, d);
    if (lane >= d) incl += t;
  }
  int run = incl - tot;  // exclusive prefix for this lane's chunk
  for (int i = 0; i < 64; ++i) {
    start[base + i] = run;
    cursor[base + i] = run;
    run += cnt[base + i];
  }
  if (lane == 63) start[NBLK3] = run;  // == N_PART
}

// ---------------- pass 3: scatter particle indices into sorted order ----------------
__global__ __launch_bounds__(256) void k_scatter(const int* __restrict__ bid,
                                                 int* __restrict__ cursor,
                                                 int* __restrict__ sorted) {
  int n = blockIdx.x * 256 + threadIdx.x;
  if (n >= N_PART) return;
  int pos = atomicAdd(&cursor[bid[n]], 1);
  sorted[pos] = n;
}

// ---------------- P2G: one workgroup per block, LDS tile accumulation ----------------
__global__ __launch_bounds__(256) void mpm_p2g(
    const float* __restrict__ x, const float* __restrict__ v,
    const float* __restrict__ C, const float* __restrict__ stress,
    const int* __restrict__ blk_start, const int* __restrict__ sorted,
    float* __restrict__ grid /* [N_GRID3][4] */) {
  __shared__ float tile[TILE3 * 4];

  int b = blockIdx.x;
  int s = blk_start[b];
  int e = blk_start[b + 1];
  if (s == e) return;  // uniform: whole block exits together

  for (int i = threadIdx.x; i < TILE3 * 4; i += 256) tile[i] = 0.0f;
  __syncthreads();

  int obx = (b >> 8) & (NBLK - 1);
  int oby = (b >> 4) & (NBLK - 1);
  int obz = b & (NBLK - 1);
  int ox = obx * 8, oy = oby * 8, oz = obz * 8;  // node-space origin of tile

  for (int i = s + (int)threadIdx.x; i < e; i += 256) {
    int n = sorted[i];

    float px = x[n * 3 + 0], py = x[n * 3 + 1], pz = x[n * 3 + 2];
    float gx = px * INV_DX, gy = py * INV_DX, gz = pz * INV_DX;
    int bx = (int)floorf(gx - 0.5f);
    int by = (int)floorf(gy - 0.5f);
    int bz = (int)floorf(gz - 0.5f);
    float fx = gx - (float)bx, fy = gy - (float)by, fz = gz - (float)bz;

    float wx[3], wy[3], wz[3];
    wx[0] = 0.5f * (1.5f - fx) * (1.5f - fx);
    wx[1] = 0.75f - (fx - 1.0f) * (fx - 1.0f);
    wx[2] = 0.5f * (fx - 0.5f) * (fx - 0.5f);
    wy[0] = 0.5f * (1.5f - fy) * (1.5f - fy);
    wy[1] = 0.75f - (fy - 1.0f) * (fy - 1.0f);
    wy[2] = 0.5f * (fy - 0.5f) * (fy - 0.5f);
    wz[0] = 0.5f * (1.5f - fz) * (1.5f - fz);
    wz[1] = 0.75f - (fz - 1.0f) * (fz - 1.0f);
    wz[2] = 0.5f * (fz - 0.5f) * (fz - 0.5f);

    float aff[9];
#pragma unroll
    for (int k = 0; k < 9; ++k)
      aff[k] = AFF_COEF * stress[n * 9 + k] + P_MASS * C[n * 9 + k];

    float mvx = P_MASS * v[n * 3 + 0];
    float mvy = P_MASS * v[n * 3 + 1];
    float mvz = P_MASS * v[n * 3 + 2];

    int lx0 = bx - ox, ly0 = by - oy, lz0 = bz - oz;  // in [0,7]

#pragma unroll
    for (int a = 0; a < 3; ++a) {
#pragma unroll
      for (int bb = 0; bb < 3; ++bb) {
#pragma unroll
        for (int c = 0; c < 3; ++c) {
          float weight = wx[a] * wy[bb] * wz[c];
          float dpx = ((float)a - fx) * DX;
          float dpy = ((float)bb - fy) * DX;
          float dpz = ((float)c - fz) * DX;
          float m0 = mvx + aff[0] * dpx + aff[1] * dpy + aff[2] * dpz;
          float m1 = mvy + aff[3] * dpx + aff[4] * dpy + aff[5] * dpz;
          float m2 = mvz + aff[6] * dpx + aff[7] * dpy + aff[8] * dpz;
          int li = (((lx0 + a) * TILE) + (ly0 + bb)) * TILE + (lz0 + c);
          atomicAdd(&tile[li * 4 + 0], weight * m0);
          atomicAdd(&tile[li * 4 + 1], weight * m1);
          atomicAdd(&tile[li * 4 + 2], weight * m2);
          atomicAdd(&tile[li * 4 + 3], weight * P_MASS);
        }
      }
    }
  }
  __syncthreads();

  // flush tile to global grid (halo overlaps neighbor blocks -> atomic)
  for (int t = threadIdx.x; t < TILE3; t += 256) {
    float m = tile[t * 4 + 3];
    if (m != 0.0f) {
      int lz = t % TILE;
      int ly = (t / TILE) % TILE;
      int lx = t / (TILE * TILE);
      int nx = ox + lx, ny = oy + ly, nz = oz + lz;
      if (nx < N_GRID && ny < N_GRID && nz < N_GRID) {
        int flat = (nx * N_GRID + ny) * N_GRID + nz;
        atomicAdd(&grid[flat * 4 + 0], tile[t * 4 + 0]);
        atomicAdd(&grid[flat * 4 + 1], tile[t * 4 + 1]);
        atomicAdd(&grid[flat * 4 + 2], tile[t * 4 + 2]);
        atomicAdd(&grid[flat * 4 + 3], m);
      }
    }
  }
}

// ---------------- grid update: normalize, gravity, boundary ----------------
__global__ __launch_bounds__(256) void mpm_grid_op(float* __restrict__ grid) {
  int i = blockIdx.x * blockDim.x + threadIdx.x;
  if (i >= N_GRID3) return;
  float4* g4 = (float4*)grid;
  float4 g = g4[i];
  float m = g.w;
  float vx = 0.0f, vy = 0.0f, vz = 0.0f;
  if (m > 0.0f) {
    float inv = 1.0f / fmaxf(m, 1e-10f);
    vx = g.x * inv;
    vy = g.y * inv;
    vz = g.z * inv;
    vy -= DT * GRAVITY;
  }
  int iz = i & (N_GRID - 1);
  int iy = (i >> 7) & (N_GRID - 1);
  int ix = i >> 14;
  if (ix < BOUND && vx < 0.0f) vx = 0.0f;
  if (ix >= N_GRID - BOUND && vx > 0.0f) vx = 0.0f;
  if (iy < BOUND && vy < 0.0f) vy = 0.0f;
  if (iy >= N_GRID - BOUND && vy > 0.0f) vy = 0.0f;
  if (iz < BOUND && vz < 0.0f) vz = 0.0f;
  if (iz >= N_GRID - BOUND && vz > 0.0f) vz = 0.0f;
  g4[i] = make_float4(vx, vy, vz, m);
}

// ---------------- G2P: gather grid velocity back to particles ----------------
__global__ __launch_bounds__(256) void mpm_g2p(
    const float* __restrict__ x, const float* __restrict__ F,
    const float* __restrict__ grid,
    float* __restrict__ out_x, float* __restrict__ out_v,
    float* __restrict__ out_C, float* __restrict__ out_F) {
  int n = blockIdx.x * blockDim.x + threadIdx.x;
  if (n >= N_PART) return;

  float px = x[n * 3 + 0], py = x[n * 3 + 1], pz = x[n * 3 + 2];
  float gx = px * INV_DX, gy = py * INV_DX, gz = pz * INV_DX;
  int bx = (int)floorf(gx - 0.5f);
  int by = (int)floorf(gy - 0.5f);
  int bz = (int)floorf(gz - 0.5f);
  float fx = gx - (float)bx, fy = gy - (float)by, fz = gz - (float)bz;

  float wx[3], wy[3], wz[3];
  wx[0] = 0.5f * (1.5f - fx) * (1.5f - fx);
  wx[1] = 0.75f - (fx - 1.0f) * (fx - 1.0f);
  wx[2] = 0.5f * (fx - 0.5f) * (fx - 0.5f);
  wy[0] = 0.5f * (1.5f - fy) * (1.5f - fy);
  wy[1] = 0.75f - (fy - 1.0f) * (fy - 1.0f);
  wy[2] = 0.5f * (fy - 0.5f) * (fy - 0.5f);
  wz[0] = 0.5f * (1.5f - fz) * (1.5f - fz);
  wz[1] = 0.75f - (fz - 1.0f) * (fz - 1.0f);
  wz[2] = 0.5f * (fz - 0.5f) * (fz - 0.5f);

  float vnx = 0.0f, vny = 0.0f, vnz = 0.0f;
  float Cn[9];
#pragma unroll
  for (int i = 0; i < 9; ++i) Cn[i] = 0.0f;

  const float4* g4 = (const float4*)grid;
#pragma unroll
  for (int a = 0; a < 3; ++a) {
#pragma unroll
    for (int bb = 0; bb < 3; ++bb) {
#pragma unroll
      for (int c = 0; c < 3; ++c) {
        float weight = wx[a] * wy[bb] * wz[c];
        float dpx = ((float)a - fx) * DX;
        float dpy = ((float)bb - fy) * DX;
        float dpz = ((float)c - fz) * DX;
        int nx = min(max(bx + a, 0), N_GRID - 1);
        int ny = min(max(by + bb, 0), N_GRID - 1);
        int nz = min(max(bz + c, 0), N_GRID - 1);
        int flat = (nx * N_GRID + ny) * N_GRID + nz;
        float4 g = g4[flat];
        vnx += weight * g.x;
        vny += weight * g.y;
        vnz += weight * g.z;
        Cn[0] += weight * g.x * dpx;
        Cn[1] += weight * g.x * dpy;
        Cn[2] += weight * g.x * dpz;
        Cn[3] += weight * g.y * dpx;
        Cn[4] += weight * g.y * dpy;
        Cn[5] += weight * g.y * dpz;
        Cn[6] += weight * g.z * dpx;
        Cn[7] += weight * g.z * dpy;
        Cn[8] += weight * g.z * dpz;
      }
    }
  }

#pragma unroll
  for (int i = 0; i < 9; ++i) Cn[i] *= C_SCALE;

  out_x[n * 3 + 0] = px + DT * vnx;
  out_x[n * 3 + 1] = py + DT * vny;
  out_x[n * 3 + 2] = pz + DT * vnz;
  out_v[n * 3 + 0] = vnx;
  out_v[n * 3 + 1] = vny;
  out_v[n * 3 + 2] = vnz;

  float A[9];
#pragma unroll
  for (int i = 0; i < 9; ++i) A[i] = DT * Cn[i];
  A[0] += 1.0f; A[4] += 1.0f; A[8] += 1.0f;

  float Fl[9];
#pragma unroll
  for (int i = 0; i < 9; ++i) Fl[i] = F[n * 9 + i];

#pragma unroll
  for (int i = 0; i < 3; ++i) {
#pragma unroll
    for (int k = 0; k < 3; ++k) {
      float s = A[i * 3 + 0] * Fl[0 * 3 + k] +
                A[i * 3 + 1] * Fl[1 * 3 + k] +
                A[i * 3 + 2] * Fl[2 * 3 + k];
      out_F[n * 9 + i * 3 + k] = s;
    }
  }

#pragma unroll
  for (int i = 0; i < 9; ++i) out_C[n * 9 + i] = Cn[i];
}

extern "C" void kernel_launch(void* const* d_in, const int* in_sizes, int n_in,
                              void* d_out, int out_size, void* d_ws, size_t ws_size,
                              hipStream_t stream) {
  const float* x      = (const float*)d_in[0];
  const float* v      = (const float*)d_in[1];
  const float* C      = (const float*)d_in[2];
  const float* F      = (const float*)d_in[3];
  const float* stress = (const float*)d_in[4];

  float* out  = (float*)d_out;
  char*  ws   = (char*)d_ws;

  const size_t GRID_BYTES = (size_t)N_GRID3 * 4 * sizeof(float);  // 33.5 MB
  float* grid      = (float*)ws;
  int*   blk_count = (int*)(ws + GRID_BYTES);
  int*   blk_start = blk_count + NBLK3;            // NBLK3 + 1 entries
  int*   cursor    = blk_start + NBLK3 + 1;
  int*   bidArr    = cursor + NBLK3;
  int*   sortedIdx = bidArr + N_PART;

  hipMemsetAsync(grid, 0, GRID_BYTES, stream);
  hipMemsetAsync(blk_count, 0, NBLK3 * sizeof(int), stream);

  int pblocks = (N_PART + 255) / 256;
  k_count<<<pblocks, 256, 0, stream>>>(x, bidArr, blk_count);
  k_scan<<<1, 64, 0, stream>>>(blk_count, blk_start, cursor);
  k_scatter<<<pblocks, 256, 0, stream>>>(bidArr, cursor, sortedIdx);

  mpm_p2g<<<NBLK3, 256, 0, stream>>>(x, v, C, stress, blk_start, sortedIdx, grid);

  int gblocks = (N_GRID3 + 255) / 256;
  mpm_grid_op<<<gblocks, 256, 0, stream>>>(grid);

  float* out_x = out;
  float* out_v = out + (size_t)N_PART * 3;
  float* out_C = out + (size_t)N_PART * 6;
  float* out_F = out + (size_t)N_PART * 6 + (size_t)N_PART * 9;
  mpm_g2p<<<pblocks, 256, 0, stream>>>(x, F, grid, out_x, out_v, out_C, out_F);
}

// Round 3
// 790.022 us; speedup vs baseline: 3.6018x; 1.0010x over previous
//
#include <hip/hip_runtime.h>

#define N_GRID 128
#define N_GRID3 (N_GRID * N_GRID * N_GRID)

constexpr int   N_PART   = 500000;
constexpr float DT       = 0.0002f;
constexpr float DX       = 1.0f / 128.0f;
constexpr float INV_DX   = 128.0f;
constexpr float P_MASS   = 5.9604644775390625e-05f;   // (DX*0.5)^3 * 1000
constexpr float AFF_COEF = -7.8125e-07f;              // -DT * P_VOL * 4 * INV_DX^2
constexpr float GRAVITY  = 9.8f;
constexpr int   BOUND    = 3;
constexpr float C_SCALE  = 65536.0f;                  // 4 * INV_DX^2

constexpr int NBLK  = 16;                 // blocks per axis (8 cells each)
constexpr int NBLK3 = NBLK * NBLK * NBLK; // 4096
constexpr int TILE  = 10;                 // nodes per axis in a block tile (8 + 2 halo)
constexpr int TILE3 = TILE * TILE * TILE; // 1000

// Native fp32 atomic add (ds_add_f32 / global_atomic_add_f32), bypassing the
// HIP default CAS-loop lowering for float atomicAdd.
__device__ __forceinline__ void atomAddF(float* p, float v) {
  unsafeAtomicAdd(p, v);
}

// ---------------- pass 1: per-particle block id + histogram ----------------
__global__ __launch_bounds__(256) void k_count(const float* __restrict__ x,
                                               int* __restrict__ bid,
                                               int* __restrict__ cnt) {
  int n = blockIdx.x * 256 + threadIdx.x;
  if (n >= N_PART) return;
  int bx = (int)floorf(x[n * 3 + 0] * INV_DX - 0.5f) >> 3;
  int by = (int)floorf(x[n * 3 + 1] * INV_DX - 0.5f) >> 3;
  int bz = (int)floorf(x[n * 3 + 2] * INV_DX - 0.5f) >> 3;
  int b = (bx * NBLK + by) * NBLK + bz;
  bid[n] = b;
  atomicAdd(&cnt[b], 1);  // int atomic: native
}

// ---------------- pass 2: exclusive scan of 4096 bins (1 wave) ----------------
__global__ __launch_bounds__(64) void k_scan(const int* __restrict__ cnt,
                                             int* __restrict__ start,
                                             int* __restrict__ cursor) {
  int lane = threadIdx.x;  // 0..63, each lane owns 64 consecutive bins
  int base = lane * 64;
  int tot = 0;
  for (int i = 0; i < 64; ++i) tot += cnt[base + i];
  int incl = tot;
  for (int d = 1; d < 64; d <<= 1) {
    int t = __shfl_up(incl, d);
    if (lane >= d) incl += t;
  }
  int run = incl - tot;
  for (int i = 0; i < 64; ++i) {
    start[base + i] = run;
    cursor[base + i] = run;
    run += cnt[base + i];
  }
  if (lane == 63) start[NBLK3] = run;  // == N_PART
}

// ---------------- pass 3: scatter particle indices into sorted order ----------------
__global__ __launch_bounds__(256) void k_scatter(const int* __restrict__ bid,
                                                 int* __restrict__ cursor,
                                                 int* __restrict__ sorted) {
  int n = blockIdx.x * 256 + threadIdx.x;
  if (n >= N_PART) return;
  int pos = atomicAdd(&cursor[bid[n]], 1);  // int atomic: native
  sorted[pos] = n;
}

// ---------------- P2G: one workgroup per block, LDS tile accumulation ----------------
__global__ __launch_bounds__(256) void mpm_p2g(
    const float* __restrict__ x, const float* __restrict__ v,
    const float* __restrict__ C, const float* __restrict__ stress,
    const int* __restrict__ blk_start, const int* __restrict__ sorted,
    float* __restrict__ grid /* [N_GRID3][4] */) {
  // SoA planes: bank(tile[p][li]) = (p*1000 + li) % 32 -> lanes with distinct
  // cells spread ~uniformly over all 32 banks (vs 8 banks in AoS layout).
  __shared__ float tile[4][TILE3];

  int b = blockIdx.x;
  int s = blk_start[b];
  int e = blk_start[b + 1];
  if (s == e) return;  // uniform across block

  for (int i = threadIdx.x; i < TILE3; i += 256) {
    tile[0][i] = 0.0f; tile[1][i] = 0.0f; tile[2][i] = 0.0f; tile[3][i] = 0.0f;
  }
  __syncthreads();

  int obx = (b >> 8) & (NBLK - 1);
  int oby = (b >> 4) & (NBLK - 1);
  int obz = b & (NBLK - 1);
  int ox = obx * 8, oy = oby * 8, oz = obz * 8;

  for (int i = s + (int)threadIdx.x; i < e; i += 256) {
    int n = sorted[i];

    float px = x[n * 3 + 0], py = x[n * 3 + 1], pz = x[n * 3 + 2];
    float gx = px * INV_DX, gy = py * INV_DX, gz = pz * INV_DX;
    int bx = (int)floorf(gx - 0.5f);
    int by = (int)floorf(gy - 0.5f);
    int bz = (int)floorf(gz - 0.5f);
    float fx = gx - (float)bx, fy = gy - (float)by, fz = gz - (float)bz;

    float wx[3], wy[3], wz[3];
    wx[0] = 0.5f * (1.5f - fx) * (1.5f - fx);
    wx[1] = 0.75f - (fx - 1.0f) * (fx - 1.0f);
    wx[2] = 0.5f * (fx - 0.5f) * (fx - 0.5f);
    wy[0] = 0.5f * (1.5f - fy) * (1.5f - fy);
    wy[1] = 0.75f - (fy - 1.0f) * (fy - 1.0f);
    wy[2] = 0.5f * (fy - 0.5f) * (fy - 0.5f);
    wz[0] = 0.5f * (1.5f - fz) * (1.5f - fz);
    wz[1] = 0.75f - (fz - 1.0f) * (fz - 1.0f);
    wz[2] = 0.5f * (fz - 0.5f) * (fz - 0.5f);

    float aff[9];
#pragma unroll
    for (int k = 0; k < 9; ++k)
      aff[k] = AFF_COEF * stress[n * 9 + k] + P_MASS * C[n * 9 + k];

    float mvx = P_MASS * v[n * 3 + 0];
    float mvy = P_MASS * v[n * 3 + 1];
    float mvz = P_MASS * v[n * 3 + 2];

    int lx0 = bx - ox, ly0 = by - oy, lz0 = bz - oz;  // in [0,7]

#pragma unroll
    for (int a = 0; a < 3; ++a) {
#pragma unroll
      for (int bb = 0; bb < 3; ++bb) {
#pragma unroll
        for (int c = 0; c < 3; ++c) {
          float weight = wx[a] * wy[bb] * wz[c];
          float dpx = ((float)a - fx) * DX;
          float dpy = ((float)bb - fy) * DX;
          float dpz = ((float)c - fz) * DX;
          float m0 = mvx + aff[0] * dpx + aff[1] * dpy + aff[2] * dpz;
          float m1 = mvy + aff[3] * dpx + aff[4] * dpy + aff[5] * dpz;
          float m2 = mvz + aff[6] * dpx + aff[7] * dpy + aff[8] * dpz;
          int li = (((lx0 + a) * TILE) + (ly0 + bb)) * TILE + (lz0 + c);
          atomAddF(&tile[0][li], weight * m0);
          atomAddF(&tile[1][li], weight * m1);
          atomAddF(&tile[2][li], weight * m2);
          atomAddF(&tile[3][li], weight * P_MASS);
        }
      }
    }
  }
  __syncthreads();

  // flush tile to global grid (halo overlaps neighbor blocks -> atomic)
  for (int t = threadIdx.x; t < TILE3; t += 256) {
    float m = tile[3][t];
    if (m != 0.0f) {
      int lz = t % TILE;
      int ly = (t / TILE) % TILE;
      int lx = t / (TILE * TILE);
      int nx = ox + lx, ny = oy + ly, nz = oz + lz;
      if (nx < N_GRID && ny < N_GRID && nz < N_GRID) {
        int flat = (nx * N_GRID + ny) * N_GRID + nz;
        atomAddF(&grid[flat * 4 + 0], tile[0][t]);
        atomAddF(&grid[flat * 4 + 1], tile[1][t]);
        atomAddF(&grid[flat * 4 + 2], tile[2][t]);
        atomAddF(&grid[flat * 4 + 3], m);
      }
    }
  }
}

// ---------------- grid update: normalize, gravity, boundary ----------------
__global__ __launch_bounds__(256) void mpm_grid_op(float* __restrict__ grid) {
  int i = blockIdx.x * blockDim.x + threadIdx.x;
  if (i >= N_GRID3) return;
  float4* g4 = (float4*)grid;
  float4 g = g4[i];
  float m = g.w;
  float vx = 0.0f, vy = 0.0f, vz = 0.0f;
  if (m > 0.0f) {
    float inv = 1.0f / fmaxf(m, 1e-10f);
    vx = g.x * inv;
    vy = g.y * inv;
    vz = g.z * inv;
    vy -= DT * GRAVITY;
  }
  int iz = i & (N_GRID - 1);
  int iy = (i >> 7) & (N_GRID - 1);
  int ix = i >> 14;
  if (ix < BOUND && vx < 0.0f) vx = 0.0f;
  if (ix >= N_GRID - BOUND && vx > 0.0f) vx = 0.0f;
  if (iy < BOUND && vy < 0.0f) vy = 0.0f;
  if (iy >= N_GRID - BOUND && vy > 0.0f) vy = 0.0f;
  if (iz < BOUND && vz < 0.0f) vz = 0.0f;
  if (iz >= N_GRID - BOUND && vz > 0.0f) vz = 0.0f;
  g4[i] = make_float4(vx, vy, vz, m);
}

// ---------------- G2P: gather grid velocity back to particles ----------------
__global__ __launch_bounds__(256) void mpm_g2p(
    const float* __restrict__ x, const float* __restrict__ F,
    const float* __restrict__ grid,
    float* __restrict__ out_x, float* __restrict__ out_v,
    float* __restrict__ out_C, float* __restrict__ out_F) {
  int n = blockIdx.x * blockDim.x + threadIdx.x;
  if (n >= N_PART) return;

  float px = x[n * 3 + 0], py = x[n * 3 + 1], pz = x[n * 3 + 2];
  float gx = px * INV_DX, gy = py * INV_DX, gz = pz * INV_DX;
  int bx = (int)floorf(gx - 0.5f);
  int by = (int)floorf(gy - 0.5f);
  int bz = (int)floorf(gz - 0.5f);
  float fx = gx - (float)bx, fy = gy - (float)by, fz = gz - (float)bz;

  float wx[3], wy[3], wz[3];
  wx[0] = 0.5f * (1.5f - fx) * (1.5f - fx);
  wx[1] = 0.75f - (fx - 1.0f) * (fx - 1.0f);
  wx[2] = 0.5f * (fx - 0.5f) * (fx - 0.5f);
  wy[0] = 0.5f * (1.5f - fy) * (1.5f - fy);
  wy[1] = 0.75f - (fy - 1.0f) * (fy - 1.0f);
  wy[2] = 0.5f * (fy - 0.5f) * (fy - 0.5f);
  wz[0] = 0.5f * (1.5f - fz) * (1.5f - fz);
  wz[1] = 0.75f - (fz - 1.0f) * (fz - 1.0f);
  wz[2] = 0.5f * (fz - 0.5f) * (fz - 0.5f);

  float vnx = 0.0f, vny = 0.0f, vnz = 0.0f;
  float Cn[9];
#pragma unroll
  for (int i = 0; i < 9; ++i) Cn[i] = 0.0f;

  const float4* g4 = (const float4*)grid;
#pragma unroll
  for (int a = 0; a < 3; ++a) {
#pragma unroll
    for (int bb = 0; bb < 3; ++bb) {
#pragma unroll
      for (int c = 0; c < 3; ++c) {
        float weight = wx[a] * wy[bb] * wz[c];
        float dpx = ((float)a - fx) * DX;
        float dpy = ((float)bb - fy) * DX;
        float dpz = ((float)c - fz) * DX;
        int nx = min(max(bx + a, 0), N_GRID - 1);
        int ny = min(max(by + bb, 0), N_GRID - 1);
        int nz = min(max(bz + c, 0), N_GRID - 1);
        int flat = (nx * N_GRID + ny) * N_GRID + nz;
        float4 g = g4[flat];
        vnx += weight * g.x;
        vny += weight * g.y;
        vnz += weight * g.z;
        Cn[0] += weight * g.x * dpx;
        Cn[1] += weight * g.x * dpy;
        Cn[2] += weight * g.x * dpz;
        Cn[3] += weight * g.y * dpx;
        Cn[4] += weight * g.y * dpy;
        Cn[5] += weight * g.y * dpz;
        Cn[6] += weight * g.z * dpx;
        Cn[7] += weight * g.z * dpy;
        Cn[8] += weight * g.z * dpz;
      }
    }
  }

#pragma unroll
  for (int i = 0; i < 9; ++i) Cn[i] *= C_SCALE;

  out_x[n * 3 + 0] = px + DT * vnx;
  out_x[n * 3 + 1] = py + DT * vny;
  out_x[n * 3 + 2] = pz + DT * vnz;
  out_v[n * 3 + 0] = vnx;
  out_v[n * 3 + 1] = vny;
  out_v[n * 3 + 2] = vnz;

  float A[9];
#pragma unroll
  for (int i = 0; i < 9; ++i) A[i] = DT * Cn[i];
  A[0] += 1.0f; A[4] += 1.0f; A[8] += 1.0f;

  float Fl[9];
#pragma unroll
  for (int i = 0; i < 9; ++i) Fl[i] = F[n * 9 + i];

#pragma unroll
  for (int i = 0; i < 3; ++i) {
#pragma unroll
    for (int k = 0; k < 3; ++k) {
      float s = A[i * 3 + 0] * Fl[0 * 3 + k] +
                A[i * 3 + 1] * Fl[1 * 3 + k] +
                A[i * 3 + 2] * Fl[2 * 3 + k];
      out_F[n * 9 + i * 3 + k] = s;
    }
  }

#pragma unroll
  for (int i = 0; i < 9; ++i) out_C[n * 9 + i] = Cn[i];
}

extern "C" void kernel_launch(void* const* d_in, const int* in_sizes, int n_in,
                              void* d_out, int out_size, void* d_ws, size_t ws_size,
                              hipStream_t stream) {
  const float* x      = (const float*)d_in[0];
  const float* v      = (const float*)d_in[1];
  const float* C      = (const float*)d_in[2];
  const float* F      = (const float*)d_in[3];
  const float* stress = (const float*)d_in[4];

  float* out  = (float*)d_out;
  char*  ws   = (char*)d_ws;

  const size_t GRID_BYTES = (size_t)N_GRID3 * 4 * sizeof(float);  // 33.5 MB
  float* grid      = (float*)ws;
  int*   blk_count = (int*)(ws + GRID_BYTES);
  int*   blk_start = blk_count + NBLK3;            // NBLK3 + 1 entries
  int*   cursor    = blk_start + NBLK3 + 1;
  int*   bidArr    = cursor + NBLK3;
  int*   sortedIdx = bidArr + N_PART;

  hipMemsetAsync(grid, 0, GRID_BYTES, stream);
  hipMemsetAsync(blk_count, 0, NBLK3 * sizeof(int), stream);

  int pblocks = (N_PART + 255) / 256;
  k_count<<<pblocks, 256, 0, stream>>>(x, bidArr, blk_count);
  k_scan<<<1, 64, 0, stream>>>(blk_count, blk_start, cursor);
  k_scatter<<<pblocks, 256, 0, stream>>>(bidArr, cursor, sortedIdx);

  mpm_p2g<<<NBLK3, 256, 0, stream>>>(x, v, C, stress, blk_start, sortedIdx, grid);

  int gblocks = (N_GRID3 + 255) / 256;
  mpm_grid_op<<<gblocks, 256, 0, stream>>>(grid);

  float* out_x = out;
  float* out_v = out + (size_t)N_PART * 3;
  float* out_C = out + (size_t)N_PART * 6;
  float* out_F = out + (size_t)N_PART * 6 + (size_t)N_PART * 9;
  mpm_g2p<<<pblocks, 256, 0, stream>>>(x, F, grid, out_x, out_v, out_C, out_F);
}